// Round 10
// baseline (416.263 us; speedup 1.0000x reference)
//
#include <hip/hip_runtime.h>

#define D 96          // feature dim
#define D4 24         // float4s per row
#define XSTR 100      // Xs row stride in floats
typedef unsigned int uint;
typedef unsigned short ushort;
typedef float f32x4 __attribute__((ext_vector_type(4)));   // native vec for nontemporal builtins

// ---------- bf16 helpers (RNE) ----------
__device__ __forceinline__ ushort f2bf(float f) {
    uint u = __float_as_uint(f);
    u = (u + 0x7FFFu + ((u >> 16) & 1u)) >> 16;
    return (ushort)u;
}
__device__ __forceinline__ uint pack2(float a, float b) {
    return (uint)f2bf(a) | ((uint)f2bf(b) << 16);
}
__device__ __forceinline__ void add8(float* a, uint4 c) {
    a[0] += __uint_as_float(c.x << 16);
    a[1] += __uint_as_float(c.x & 0xFFFF0000u);
    a[2] += __uint_as_float(c.y << 16);
    a[3] += __uint_as_float(c.y & 0xFFFF0000u);
    a[4] += __uint_as_float(c.z << 16);
    a[5] += __uint_as_float(c.z & 0xFFFF0000u);
    a[6] += __uint_as_float(c.w << 16);
    a[7] += __uint_as_float(c.w & 0xFFFF0000u);
}
__device__ __forceinline__ void add4(float* a, uint4 c) {
    a[0] += __uint_as_float(c.x << 16);
    a[1] += __uint_as_float(c.x & 0xFFFF0000u);
    a[2] += __uint_as_float(c.y << 16);
    a[3] += __uint_as_float(c.y & 0xFFFF0000u);
}
__device__ __forceinline__ void set8s(float* a, uint4 c, float s) {
    a[0] = s * __uint_as_float(c.x << 16);
    a[1] = s * __uint_as_float(c.x & 0xFFFF0000u);
    a[2] = s * __uint_as_float(c.y << 16);
    a[3] = s * __uint_as_float(c.y & 0xFFFF0000u);
    a[4] = s * __uint_as_float(c.z << 16);
    a[5] = s * __uint_as_float(c.z & 0xFFFF0000u);
    a[6] = s * __uint_as_float(c.w << 16);
    a[7] = s * __uint_as_float(c.w & 0xFFFF0000u);
}
__device__ __forceinline__ void set4s(float* a, uint4 c, float s) {
    a[0] = s * __uint_as_float(c.x << 16);
    a[1] = s * __uint_as_float(c.x & 0xFFFF0000u);
    a[2] = s * __uint_as_float(c.y << 16);
    a[3] = s * __uint_as_float(c.y & 0xFFFF0000u);
}
__device__ __forceinline__ void nt_store4(float4* p, float x, float y, float z, float w) {
    f32x4 v; v.x = x; v.y = y; v.z = z; v.w = w;
    __builtin_nontemporal_store(v, (f32x4*)p);
}

// feat fp32 [N][96] -> 8 sub-tables T[g][N][2xuint4] (cols 12g..12g+11, 24B + 8B pad)
__global__ void to_bf16_8g(const float4* __restrict__ X4, uint4* __restrict__ T0, int N) {
    int t = blockIdx.x * blockDim.x + threadIdx.x;
    if (t >= N * 8) return;
    int v = t >> 3, g = t & 7;
    const float4* s = X4 + (size_t)v * D4 + g * 3;
    float4 f0 = s[0], f1 = s[1], f2 = s[2];
    uint4* d = T0 + ((size_t)g * N + v) * 2;
    d[0] = make_uint4(pack2(f0.x,f0.y), pack2(f0.z,f0.w), pack2(f1.x,f1.y), pack2(f1.z,f1.w));
    d[1] = make_uint4(pack2(f2.x,f2.y), pack2(f2.z,f2.w), 0u, 0u);
}

// ======================= CSR build =======================

__global__ void hist_kernel(const int* __restrict__ dst, int* __restrict__ deg, int E) {
    int e = blockIdx.x * blockDim.x + threadIdx.x;
    if (e < E) atomicAdd(&deg[dst[e]], 1);
}

__global__ void block_sums(const int* __restrict__ deg, int* __restrict__ bsums, int N) {
    __shared__ int s[256];
    int t = threadIdx.x;
    int base = blockIdx.x * 1024 + t * 4;
    int sum = 0;
#pragma unroll
    for (int j = 0; j < 4; ++j) { int i = base + j; if (i < N) sum += deg[i]; }
    s[t] = sum; __syncthreads();
    for (int off = 128; off > 0; off >>= 1) {
        if (t < off) s[t] += s[t + off];
        __syncthreads();
    }
    if (t == 0) bsums[blockIdx.x] = s[0];
}

__global__ void scan_small(const int* __restrict__ bsums, int* __restrict__ boff,
                           int* __restrict__ total_out, int nb) {
    if (threadIdx.x == 0 && blockIdx.x == 0) {
        int acc = 0;
        for (int i = 0; i < nb; ++i) { boff[i] = acc; acc += bsums[i]; }
        *total_out = acc;
    }
}

__global__ void scan_write(const int* __restrict__ deg, const int* __restrict__ boff,
                           int* __restrict__ rowptr, int N) {
    __shared__ int s[256];
    int t = threadIdx.x;
    int base = blockIdx.x * 1024 + t * 4;
    int v[4]; int tsum = 0;
#pragma unroll
    for (int j = 0; j < 4; ++j) { int i = base + j; v[j] = (i < N) ? deg[i] : 0; tsum += v[j]; }
    s[t] = tsum; __syncthreads();
    for (int off = 1; off < 256; off <<= 1) {
        int x = (t >= off) ? s[t - off] : 0;
        __syncthreads();
        s[t] += x;
        __syncthreads();
    }
    int excl = s[t] - tsum + boff[blockIdx.x];
#pragma unroll
    for (int j = 0; j < 4; ++j) { int i = base + j; if (i < N) rowptr[i] = excl; excl += v[j]; }
}

__global__ void fill_edges(const int* __restrict__ src, const int* __restrict__ dst,
                           int* __restrict__ cursor, int* __restrict__ esrc, int E) {
    int e = blockIdx.x * blockDim.x + threadIdx.x;
    if (e >= E) return;
    int pos = atomicAdd(&cursor[dst[e]], 1);
    esrc[pos] = src[e];
}

// ======================= gather, XCD-pinned via HW_REG_XCC_ID =======================
// Work unit = (group g, node-block t). Block reads its REAL XCD id and claims a
// unit of group g=xcc via atomic counter; overflow-scan guarantees coverage.
// Each XCD then randomly reads ONLY its 1.6MB sub-table -> L2-resident.
// Streams (esrc, agg) use nontemporal to avoid evicting the table.
__global__ __launch_bounds__(256) void gather8(
    const uint4* __restrict__ T0, const int* __restrict__ rowptr,
    const int* __restrict__ esrc, const float* __restrict__ eps_p,
    float4* __restrict__ agg4, int* __restrict__ ctr, int N) {
    __shared__ int s_unit;
    int nbNode = (N + 255) >> 8;
    if (threadIdx.x == 0) {
        uint xcc;
        asm volatile("s_getreg_b32 %0, hwreg(HW_REG_XCC_ID)" : "=s"(xcc));
        int g = (int)(xcc & 7u);
        int t = atomicAdd(&ctr[g], 1);
        if (t >= nbNode) {
            t = -1;
            for (int gg = 0; gg < 8 && t < 0; ++gg) {
                int tt = atomicAdd(&ctr[gg], 1);
                if (tt < nbNode) { g = gg; t = tt; }
            }
        }
        s_unit = (t < 0) ? -1 : (g * nbNode + t);
    }
    __syncthreads();
    int unit = s_unit;
    if (unit < 0) return;
    int g = unit / nbNode, nb = unit - g * nbNode;
    int v = nb * 256 + threadIdx.x;
    if (v >= N) return;

    const uint4* T = T0 + (size_t)g * N * 2;
    float a[12];
    {
        uint4 c0 = T[(size_t)v * 2 + 0];
        uint4 c1 = T[(size_t)v * 2 + 1];
        float s = 1.0f + eps_p[0];
        set8s(a, c0, s); set4s(a + 8, c1, s);
    }
    int e = rowptr[v], e1 = rowptr[v + 1];
    for (; e + 1 < e1; e += 2) {
        int u0 = __builtin_nontemporal_load(&esrc[e]);
        int u1 = __builtin_nontemporal_load(&esrc[e + 1]);
        uint4 c00 = T[(size_t)u0 * 2 + 0];
        uint4 c01 = T[(size_t)u0 * 2 + 1];
        uint4 c10 = T[(size_t)u1 * 2 + 0];
        uint4 c11 = T[(size_t)u1 * 2 + 1];
        add8(a, c00); add4(a + 8, c01);
        add8(a, c10); add4(a + 8, c11);
    }
    if (e < e1) {
        int u0 = __builtin_nontemporal_load(&esrc[e]);
        uint4 c0 = T[(size_t)u0 * 2 + 0];
        uint4 c1 = T[(size_t)u0 * 2 + 1];
        add8(a, c0); add4(a + 8, c1);
    }
    float4* dst = agg4 + ((size_t)g * N + v) * 3;
    nt_store4(dst + 0, a[0], a[1], a[2], a[3]);
    nt_store4(dst + 1, a[4], a[5], a[6], a[7]);
    nt_store4(dst + 2, a[8], a[9], a[10], a[11]);
}

// ======================= MLP (2x GEMM+ReLU) =======================
// 64 rows/block, 256 threads. Stage agg[8][N][12] -> Xs rows; wave-uniform W
// (scalar loads); outputs: fp32 Y (optional) and/or bf16 sub-tables Yb (optional).
__global__ __launch_bounds__(256) void mlp96(
    const float4* __restrict__ agg4,
    const float* __restrict__ Wa, const float* __restrict__ ba,
    const float* __restrict__ Wb, const float* __restrict__ bb,
    float* __restrict__ Y, uint4* __restrict__ Yb, int N) {
    __shared__ float Xs[64 * XSTR];
    int tid = threadIdx.x;
    int R0 = blockIdx.x * 64;

    // stage: 8 regions x [64 rows][3 float4] -> Xs
#pragma unroll
    for (int i = 0; i < 6; ++i) {
        int idx = tid + i * 256;            // 0..1535
        int g = idx / 192;
        int j = idx - g * 192;
        int row = j / 3, c4 = j - row * 3;
        float4 val = make_float4(0.f, 0.f, 0.f, 0.f);
        if (R0 + row < N) val = agg4[((size_t)g * N + R0 + row) * 3 + c4];
        *(float4*)&Xs[row * XSTR + g * 12 + c4 * 4] = val;
    }
    __syncthreads();

    int lane = tid & 63;
    int c0 = __builtin_amdgcn_readfirstlane(tid >> 6) * 24;

    float acc[24];
#pragma unroll
    for (int j = 0; j < 24; ++j) acc[j] = ba[c0 + j];
#pragma unroll 2
    for (int k0 = 0; k0 < D; k0 += 4) {
        float4 xv = *(const float4*)&Xs[lane * XSTR + k0];
        const float* xf = (const float*)&xv;
#pragma unroll
        for (int kk = 0; kk < 4; ++kk) {
            float xx = xf[kk];
            const float* wr = &Wa[(k0 + kk) * D + c0];
#pragma unroll
            for (int j = 0; j < 24; ++j) acc[j] = fmaf(xx, wr[j], acc[j]);
        }
    }
    __syncthreads();

#pragma unroll
    for (int j = 0; j < 24; j += 4) {
        float4 h = make_float4(fmaxf(acc[j+0],0.f), fmaxf(acc[j+1],0.f),
                               fmaxf(acc[j+2],0.f), fmaxf(acc[j+3],0.f));
        *(float4*)&Xs[lane * XSTR + c0 + j] = h;
    }
    __syncthreads();

    float acc2[24];
#pragma unroll
    for (int j = 0; j < 24; ++j) acc2[j] = bb[c0 + j];
#pragma unroll 2
    for (int k0 = 0; k0 < D; k0 += 4) {
        float4 xv = *(const float4*)&Xs[lane * XSTR + k0];
        const float* xf = (const float*)&xv;
#pragma unroll
        for (int kk = 0; kk < 4; ++kk) {
            float xx = xf[kk];
            const float* wr = &Wb[(k0 + kk) * D + c0];
#pragma unroll
            for (int j = 0; j < 24; ++j) acc2[j] = fmaf(xx, wr[j], acc2[j]);
        }
    }
    __syncthreads();

#pragma unroll
    for (int j = 0; j < 24; j += 4) {
        float4 o = make_float4(fmaxf(acc2[j+0],0.f), fmaxf(acc2[j+1],0.f),
                               fmaxf(acc2[j+2],0.f), fmaxf(acc2[j+3],0.f));
        *(float4*)&Xs[lane * XSTR + c0 + j] = o;
    }
    __syncthreads();

    if (Y) {
        int r = tid >> 2, q = tid & 3;
        int v = R0 + r;
        if (v < N) {
            float4* Y4 = (float4*)Y;
#pragma unroll
            for (int k = 0; k < 6; ++k)
                Y4[v * D4 + k * 4 + q] = *(const float4*)&Xs[r * XSTR + (k * 4 + q) * 4];
        }
    }
    if (Yb) {
#pragma unroll
        for (int k = 0; k < 4; ++k) {
            int c = tid + 256 * k;          // 0..1023 = 64 rows x 8 groups x 2 parts
            int row = c >> 4, rem = c & 15;
            int g = rem >> 1, part = rem & 1;
            int v = R0 + row;
            if (v < N) {
                const float* p = &Xs[row * XSTR + g * 12 + part * 8];
                uint4 o;
                if (part == 0) {
                    float4 f0 = *(const float4*)p;
                    float4 f1 = *(const float4*)(p + 4);
                    o = make_uint4(pack2(f0.x,f0.y), pack2(f0.z,f0.w),
                                   pack2(f1.x,f1.y), pack2(f1.z,f1.w));
                } else {
                    float4 f2 = *(const float4*)p;
                    o = make_uint4(pack2(f2.x,f2.y), pack2(f2.z,f2.w), 0u, 0u);
                }
                Yb[((size_t)g * N + v) * 2 + part] = o;
            }
        }
    }
}

// ======================= tier-2 fallback: fused fp32 layer (R6-proven) =======================
__global__ __launch_bounds__(256) void gin_layer_f32(
    const float* __restrict__ X, const int* __restrict__ rowptr,
    const int* __restrict__ esrc, const float* __restrict__ eps_p,
    const float* __restrict__ Wa, const float* __restrict__ ba,
    const float* __restrict__ Wb, const float* __restrict__ bb,
    float* __restrict__ Y, int N) {
    __shared__ float Xs[64 * XSTR];
    int tid = threadIdx.x;
    int R0 = blockIdx.x * 64;
    {
        int r = tid >> 2, q = tid & 3;
        int v = R0 + r;
        float a[24];
        if (v < N) {
            const float4* X4 = (const float4*)X;
            float s = 1.0f + eps_p[0];
#pragma unroll
            for (int i = 0; i < 6; ++i) {
                float4 xv = X4[v * D4 + 6 * q + i];
                a[4*i+0]=s*xv.x; a[4*i+1]=s*xv.y; a[4*i+2]=s*xv.z; a[4*i+3]=s*xv.w;
            }
            int e = rowptr[v], e1 = rowptr[v + 1];
            for (; e < e1; ++e) {
                int u = esrc[e] * D4 + 6 * q;
#pragma unroll
                for (int i = 0; i < 6; ++i) {
                    float4 m = X4[u + i];
                    a[4*i+0]+=m.x; a[4*i+1]+=m.y; a[4*i+2]+=m.z; a[4*i+3]+=m.w;
                }
            }
        } else {
#pragma unroll
            for (int j = 0; j < 24; ++j) a[j] = 0.f;
        }
#pragma unroll
        for (int i = 0; i < 6; ++i)
            *(float4*)&Xs[r * XSTR + q * 24 + 4 * i] =
                make_float4(a[4*i], a[4*i+1], a[4*i+2], a[4*i+3]);
    }
    __syncthreads();
    int lane = tid & 63;
    int c0 = __builtin_amdgcn_readfirstlane(tid >> 6) * 24;
    float acc[24];
#pragma unroll
    for (int j = 0; j < 24; ++j) acc[j] = ba[c0 + j];
#pragma unroll 2
    for (int k0 = 0; k0 < D; k0 += 4) {
        float4 xv = *(const float4*)&Xs[lane * XSTR + k0];
        const float* xf = (const float*)&xv;
#pragma unroll
        for (int kk = 0; kk < 4; ++kk) {
            float xx = xf[kk];
            const float* wr = &Wa[(k0 + kk) * D + c0];
#pragma unroll
            for (int j = 0; j < 24; ++j) acc[j] = fmaf(xx, wr[j], acc[j]);
        }
    }
    __syncthreads();
#pragma unroll
    for (int j = 0; j < 24; j += 4) {
        float4 h = make_float4(fmaxf(acc[j+0],0.f), fmaxf(acc[j+1],0.f),
                               fmaxf(acc[j+2],0.f), fmaxf(acc[j+3],0.f));
        *(float4*)&Xs[lane * XSTR + c0 + j] = h;
    }
    __syncthreads();
    float acc2[24];
#pragma unroll
    for (int j = 0; j < 24; ++j) acc2[j] = bb[c0 + j];
#pragma unroll 2
    for (int k0 = 0; k0 < D; k0 += 4) {
        float4 xv = *(const float4*)&Xs[lane * XSTR + k0];
        const float* xf = (const float*)&xv;
#pragma unroll
        for (int kk = 0; kk < 4; ++kk) {
            float xx = xf[kk];
            const float* wr = &Wb[(k0 + kk) * D + c0];
#pragma unroll
            for (int j = 0; j < 24; ++j) acc2[j] = fmaf(xx, wr[j], acc2[j]);
        }
    }
    __syncthreads();
#pragma unroll
    for (int j = 0; j < 24; j += 4) {
        float4 o = make_float4(fmaxf(acc2[j+0],0.f), fmaxf(acc2[j+1],0.f),
                               fmaxf(acc2[j+2],0.f), fmaxf(acc2[j+3],0.f));
        *(float4*)&Xs[lane * XSTR + c0 + j] = o;
    }
    __syncthreads();
    {
        int r = tid >> 2, q = tid & 3;
        int v = R0 + r;
        if (v < N) {
            float4* Y4 = (float4*)Y;
#pragma unroll
            for (int k = 0; k < 6; ++k)
                Y4[v * D4 + k * 4 + q] = *(const float4*)&Xs[r * XSTR + (k * 4 + q) * 4];
        }
    }
}

// ======================= launch =======================

extern "C" void kernel_launch(void* const* d_in, const int* in_sizes, int n_in,
                              void* d_out, int out_size, void* d_ws, size_t ws_size,
                              hipStream_t stream) {
    const float* feat = (const float*)d_in[0];
    const int*   src  = (const int*)d_in[1];
    const int*   dst  = (const int*)d_in[2];
    const float* eps1 = (const float*)d_in[3];
    const float* W1a  = (const float*)d_in[4];
    const float* b1a  = (const float*)d_in[5];
    const float* W1b  = (const float*)d_in[6];
    const float* b1b  = (const float*)d_in[7];
    const float* eps2 = (const float*)d_in[8];
    const float* W2a  = (const float*)d_in[9];
    const float* b2a  = (const float*)d_in[10];
    const float* W2b  = (const float*)d_in[11];
    const float* b2b  = (const float*)d_in[12];

    int N = in_sizes[0] / D;     // 50000
    int E = in_sizes[1];         // 800000

    float* out = (float*)d_out;

    char* w = (char*)d_ws;
    size_t off = 0;
    auto carve = [&](size_t bytes) -> void* {
        void* p = w + off;
        off += (bytes + 255) & ~(size_t)255;
        return p;
    };
    int*   rowptr = (int*)carve((size_t)(N + 1) * sizeof(int));
    int*   deg    = (int*)carve((size_t)N * sizeof(int));
    int*   cursor = (int*)carve((size_t)N * sizeof(int));
    int*   esrc   = (int*)carve((size_t)E * sizeof(int));
    int nb = (N + 1023) / 1024;
    int*   bsums  = (int*)carve((size_t)nb * sizeof(int));
    int*   boff   = (int*)carve((size_t)nb * sizeof(int));
    int*   ctr    = (int*)carve(16 * sizeof(int));
    bool csr_ok = (off <= ws_size);
    size_t base = off;
    uint4* tab   = (uint4*)carve((size_t)8 * N * 2 * sizeof(uint4));   // 12.8 MB
    float* agg   = (float*)carve((size_t)8 * N * 12 * sizeof(float));  // 19.2 MB
    bool full_ok = (off <= ws_size);
    float* A = (float*)(w + base);                                     // tier-2 alias
    bool a_ok = (base + (size_t)N * D * sizeof(float) <= ws_size);

    int eGrid = (E + 255) / 256;
    int mlpGrid = (N + 63) / 64;
    int nbNode = (N + 255) / 256;
    int gatherGrid = 8 * nbNode;
    int cvtGrid = (N * 8 + 255) / 256;

    if (csr_ok && a_ok) {
        // ---- CSR build ----
        (void)hipMemsetAsync(deg, 0, (size_t)N * sizeof(int), stream);
        (void)hipMemsetAsync(ctr, 0, 16 * sizeof(int), stream);
        hist_kernel<<<eGrid, 256, 0, stream>>>(dst, deg, E);
        block_sums<<<nb, 256, 0, stream>>>(deg, bsums, N);
        scan_small<<<1, 64, 0, stream>>>(bsums, boff, rowptr + N, nb);
        scan_write<<<nb, 256, 0, stream>>>(deg, boff, rowptr, N);
        (void)hipMemcpyAsync(cursor, rowptr, (size_t)N * sizeof(int),
                             hipMemcpyDeviceToDevice, stream);
        fill_edges<<<eGrid, 256, 0, stream>>>(src, dst, cursor, esrc, E);

        if (full_ok) {
            float4* agg4 = (float4*)agg;
            to_bf16_8g<<<cvtGrid, 256, 0, stream>>>((const float4*)feat, tab, N);
            // layer 1
            gather8<<<gatherGrid, 256, 0, stream>>>(tab, rowptr, esrc, eps1, agg4, ctr, N);
            mlp96<<<mlpGrid, 256, 0, stream>>>(agg4, W1a, b1a, W1b, b1b, nullptr, tab, N);
            // layer 2
            gather8<<<gatherGrid, 256, 0, stream>>>(tab, rowptr, esrc, eps2, agg4, ctr + 8, N);
            mlp96<<<mlpGrid, 256, 0, stream>>>(agg4, W2a, b2a, W2b, b2b, out, nullptr, N);
        } else {
            gin_layer_f32<<<mlpGrid, 256, 0, stream>>>(feat, rowptr, esrc, eps1,
                                                       W1a, b1a, W1b, b1b, A, N);
            gin_layer_f32<<<mlpGrid, 256, 0, stream>>>(A, rowptr, esrc, eps2,
                                                       W2a, b2a, W2b, b2b, out, N);
        }
    }
}

// Round 11
// 348.834 us; speedup vs baseline: 1.1933x; 1.1933x over previous
//
#include <hip/hip_runtime.h>

#define D 96
#define D4 24
#define XSTR 100
#define NBK 8          // dst-range buckets == XCDs
#define LCAP 512       // per-bucket LDS entries per tile
#define TILE 2048      // edges per bucketA block
#define CHK 2048       // entries per claim chunk
typedef unsigned int uint;
typedef unsigned short ushort;

__device__ __forceinline__ int imin(int a, int b) { return a < b ? a : b; }

// ---------- bf16 helpers (RNE) ----------
__device__ __forceinline__ ushort f2bf(float f) {
    uint u = __float_as_uint(f);
    u = (u + 0x7FFFu + ((u >> 16) & 1u)) >> 16;
    return (ushort)u;
}
__device__ __forceinline__ uint pack2(float a, float b) {
    return (uint)f2bf(a) | ((uint)f2bf(b) << 16);
}
__device__ __forceinline__ void add8(float* a, uint4 c) {
    a[0] += __uint_as_float(c.x << 16);
    a[1] += __uint_as_float(c.x & 0xFFFF0000u);
    a[2] += __uint_as_float(c.y << 16);
    a[3] += __uint_as_float(c.y & 0xFFFF0000u);
    a[4] += __uint_as_float(c.z << 16);
    a[5] += __uint_as_float(c.z & 0xFFFF0000u);
    a[6] += __uint_as_float(c.w << 16);
    a[7] += __uint_as_float(c.w & 0xFFFF0000u);
}
__device__ __forceinline__ void set8s(float* a, uint4 c, float s) {
    a[0] = s * __uint_as_float(c.x << 16);
    a[1] = s * __uint_as_float(c.x & 0xFFFF0000u);
    a[2] = s * __uint_as_float(c.y << 16);
    a[3] = s * __uint_as_float(c.y & 0xFFFF0000u);
    a[4] = s * __uint_as_float(c.z << 16);
    a[5] = s * __uint_as_float(c.z & 0xFFFF0000u);
    a[6] = s * __uint_as_float(c.w << 16);
    a[7] = s * __uint_as_float(c.w & 0xFFFF0000u);
}

// fp32 [N][96] -> bf16 chunks [N*12] uint4
__global__ void to_bf16(const float4* __restrict__ X4, uint4* __restrict__ Xb4, int nchunk) {
    int i = blockIdx.x * blockDim.x + threadIdx.x;
    if (i >= nchunk) return;
    float4 a = X4[2 * i], b = X4[2 * i + 1];
    uint4 o;
    o.x = pack2(a.x, a.y); o.y = pack2(a.z, a.w);
    o.z = pack2(b.x, b.y); o.w = pack2(b.z, b.w);
    Xb4[i] = o;
}

// ======================= bucketed CSR build =======================
// Phase A: partition edges into 8 dst-range buckets, LDS-staged coalesced flushes.
__global__ __launch_bounds__(256) void bucketA(
    const int* __restrict__ src, const int* __restrict__ dst,
    uint2* __restrict__ bstage, int* __restrict__ bctr, int E, int N, int CAP) {
    __shared__ uint2 lbuf[NBK][LCAP];          // 32 KB
    __shared__ int cnt[NBK], basep[NBK], pfx[NBK + 1];
    int tid = threadIdx.x;
    if (tid < NBK) cnt[tid] = 0;
    __syncthreads();
    int e0 = blockIdx.x * TILE;
    int bsz = (N + NBK - 1) / NBK;
#pragma unroll
    for (int i = 0; i < TILE / 256; ++i) {
        int e = e0 + tid + i * 256;
        if (e < E) {
            int s = src[e], d = dst[e];
            int b = d / bsz;
            int pos = atomicAdd(&cnt[b], 1);
            if (pos < LCAP) lbuf[b][pos] = make_uint2((uint)s, (uint)d);
            else {                                   // ~never (16 sigma)
                int gp = atomicAdd(&bctr[b], 1);
                if (gp < CAP) bstage[(size_t)b * CAP + gp] = make_uint2((uint)s, (uint)d);
            }
        }
    }
    __syncthreads();
    if (tid == 0) {
        int acc = 0;
        for (int b = 0; b < NBK; ++b) { pfx[b] = acc; acc += imin(cnt[b], LCAP); }
        pfx[NBK] = acc;
    }
    __syncthreads();
    if (tid < NBK) {
        int c = imin(cnt[tid], LCAP);
        basep[tid] = (c > 0) ? atomicAdd(&bctr[tid], c) : 0;
    }
    __syncthreads();
    int total = pfx[NBK];
    for (int idx = tid; idx < total; idx += 256) {
        int b = 0;
        while (idx >= pfx[b + 1]) ++b;
        int j = idx - pfx[b];
        int gp = basep[b] + j;
        if (gp < CAP) bstage[(size_t)b * CAP + gp] = lbuf[b][j];
    }
}

// Phase B skeleton: XCD claims chunks of its own bucket (fallback-scan for coverage).
// MODE 0: histogram (deg). MODE 1: fill (esrc).
template <int MODE>
__global__ __launch_bounds__(256) void phaseB(
    const uint2* __restrict__ bstage, const int* __restrict__ bctr,
    int* __restrict__ claim, int* __restrict__ deg,
    const int* __restrict__ rowptr, int* __restrict__ cursor,
    int* __restrict__ esrc, int CAP) {
    __shared__ int s_b, s_t;
    while (true) {
        if (threadIdx.x == 0) {
            uint xcc;
            asm volatile("s_getreg_b32 %0, hwreg(HW_REG_XCC_ID)" : "=s"(xcc));
            int g = (int)(xcc & 7u);
            int need = (imin(bctr[g], CAP) + CHK - 1) / CHK;
            int t = atomicAdd(&claim[g], 1);
            if (t >= need) {
                t = -1;
                for (int gg = 0; gg < NBK && t < 0; ++gg) {
                    int need2 = (imin(bctr[gg], CAP) + CHK - 1) / CHK;
                    int tt = atomicAdd(&claim[gg], 1);
                    if (tt < need2) { g = gg; t = tt; }
                }
            }
            s_b = g; s_t = t;
        }
        __syncthreads();
        int b = s_b, t = s_t;
        if (t < 0) return;
        int nE = imin(bctr[b], CAP);
        int base = t * CHK;
        for (int i = threadIdx.x; i < CHK; i += 256) {
            int idx = base + i;
            if (idx < nE) {
                uint2 p = bstage[(size_t)b * CAP + idx];
                int d = (int)p.y;
                if (MODE == 0) {
                    atomicAdd(&deg[d], 1);
                } else {
                    int pos = rowptr[d] + atomicAdd(&cursor[d], 1);
                    esrc[pos] = (int)p.x;
                }
            }
        }
        __syncthreads();
    }
}

// ---- scans (proven) ----
__global__ void block_sums(const int* __restrict__ deg, int* __restrict__ bsums, int N) {
    __shared__ int s[256];
    int t = threadIdx.x;
    int base = blockIdx.x * 1024 + t * 4;
    int sum = 0;
#pragma unroll
    for (int j = 0; j < 4; ++j) { int i = base + j; if (i < N) sum += deg[i]; }
    s[t] = sum; __syncthreads();
    for (int off = 128; off > 0; off >>= 1) {
        if (t < off) s[t] += s[t + off];
        __syncthreads();
    }
    if (t == 0) bsums[blockIdx.x] = s[0];
}
__global__ void scan_small(const int* __restrict__ bsums, int* __restrict__ boff,
                           int* __restrict__ total_out, int nb) {
    if (threadIdx.x == 0 && blockIdx.x == 0) {
        int acc = 0;
        for (int i = 0; i < nb; ++i) { boff[i] = acc; acc += bsums[i]; }
        *total_out = acc;
    }
}
__global__ void scan_write(const int* __restrict__ deg, const int* __restrict__ boff,
                           int* __restrict__ rowptr, int N) {
    __shared__ int s[256];
    int t = threadIdx.x;
    int base = blockIdx.x * 1024 + t * 4;
    int v[4]; int tsum = 0;
#pragma unroll
    for (int j = 0; j < 4; ++j) { int i = base + j; v[j] = (i < N) ? deg[i] : 0; tsum += v[j]; }
    s[t] = tsum; __syncthreads();
    for (int off = 1; off < 256; off <<= 1) {
        int x = (t >= off) ? s[t - off] : 0;
        __syncthreads();
        s[t] += x;
        __syncthreads();
    }
    int excl = s[t] - tsum + boff[blockIdx.x];
#pragma unroll
    for (int j = 0; j < 4; ++j) { int i = base + j; if (i < N) rowptr[i] = excl; excl += v[j]; }
}

// ---- fallback CSR kernels (R6-proven) ----
__global__ void hist_kernel(const int* __restrict__ dst, int* __restrict__ deg, int E) {
    int e = blockIdx.x * blockDim.x + threadIdx.x;
    if (e < E) atomicAdd(&deg[dst[e]], 1);
}
__global__ void fill_edges(const int* __restrict__ src, const int* __restrict__ dst,
                           int* __restrict__ cursor, int* __restrict__ esrc, int E) {
    int e = blockIdx.x * blockDim.x + threadIdx.x;
    if (e >= E) return;
    int pos = atomicAdd(&cursor[dst[e]], 1);
    esrc[pos] = src[e];
}

// ======================= fused GIN layer (R6 structure, self from bf16 table) ==========
// Block = 64 nodes, 256 threads. Gather: 4 threads/node (r=tid>>2, q=tid&3), thread q
// owns cols [24q,24q+24): reads chunks cb=3q..3q+2 (48B contiguous per lane; lanes 0-3
// cover the full 192B row). MLP: wave-uniform W (scalar loads). Outputs optional fp32 /
// bf16 table.
__global__ __launch_bounds__(256) void gin_layer_bf16(
    const uint4* __restrict__ Xb, const int* __restrict__ rowptr,
    const int* __restrict__ esrc, const float* __restrict__ eps_p,
    const float* __restrict__ Wa, const float* __restrict__ ba,
    const float* __restrict__ Wb, const float* __restrict__ bb,
    float* __restrict__ Y, uint4* __restrict__ Yb, int N) {
    __shared__ float Xs[64 * XSTR];
    int tid = threadIdx.x;
    int R0 = blockIdx.x * 64;

    // ---------- gather ----------
    {
        int r = tid >> 2, q = tid & 3;
        int v = R0 + r;
        float a[24];
        if (v < N) {
            int cb = 3 * q;
            float s = 1.0f + eps_p[0];
            const uint4* rp = Xb + (size_t)v * 12 + cb;
            uint4 c0 = rp[0], c1 = rp[1], c2 = rp[2];
            set8s(a, c0, s); set8s(a + 8, c1, s); set8s(a + 16, c2, s);
            int e = rowptr[v], e1 = rowptr[v + 1];
            for (; e + 1 < e1; e += 2) {
                const uint4* r0 = Xb + (size_t)esrc[e] * 12 + cb;
                const uint4* r1 = Xb + (size_t)esrc[e + 1] * 12 + cb;
                uint4 c00 = r0[0], c01 = r0[1], c02 = r0[2];
                uint4 c10 = r1[0], c11 = r1[1], c12 = r1[2];
                add8(a + 0, c00); add8(a + 8, c01); add8(a + 16, c02);
                add8(a + 0, c10); add8(a + 8, c11); add8(a + 16, c12);
            }
            if (e < e1) {
                const uint4* r0 = Xb + (size_t)esrc[e] * 12 + cb;
                add8(a + 0, r0[0]); add8(a + 8, r0[1]); add8(a + 16, r0[2]);
            }
        } else {
#pragma unroll
            for (int j = 0; j < 24; ++j) a[j] = 0.f;
        }
#pragma unroll
        for (int i = 0; i < 6; ++i)
            *(float4*)&Xs[r * XSTR + q * 24 + 4 * i] =
                make_float4(a[4*i], a[4*i+1], a[4*i+2], a[4*i+3]);
    }
    __syncthreads();

    // ---------- MLP ----------
    int lane = tid & 63;
    int c0 = __builtin_amdgcn_readfirstlane(tid >> 6) * 24;

    float acc[24];
#pragma unroll
    for (int j = 0; j < 24; ++j) acc[j] = ba[c0 + j];
#pragma unroll 2
    for (int k0 = 0; k0 < D; k0 += 4) {
        float4 xv = *(const float4*)&Xs[lane * XSTR + k0];
        const float* xf = (const float*)&xv;
#pragma unroll
        for (int kk = 0; kk < 4; ++kk) {
            float x = xf[kk];
            const float* wr = &Wa[(k0 + kk) * D + c0];
#pragma unroll
            for (int j = 0; j < 24; ++j) acc[j] = fmaf(x, wr[j], acc[j]);
        }
    }
    __syncthreads();
#pragma unroll
    for (int j = 0; j < 24; j += 4) {
        float4 h = make_float4(fmaxf(acc[j+0],0.f), fmaxf(acc[j+1],0.f),
                               fmaxf(acc[j+2],0.f), fmaxf(acc[j+3],0.f));
        *(float4*)&Xs[lane * XSTR + c0 + j] = h;
    }
    __syncthreads();

    float acc2[24];
#pragma unroll
    for (int j = 0; j < 24; ++j) acc2[j] = bb[c0 + j];
#pragma unroll 2
    for (int k0 = 0; k0 < D; k0 += 4) {
        float4 xv = *(const float4*)&Xs[lane * XSTR + k0];
        const float* xf = (const float*)&xv;
#pragma unroll
        for (int kk = 0; kk < 4; ++kk) {
            float x = xf[kk];
            const float* wr = &Wb[(k0 + kk) * D + c0];
#pragma unroll
            for (int j = 0; j < 24; ++j) acc2[j] = fmaf(x, wr[j], acc2[j]);
        }
    }
    __syncthreads();
#pragma unroll
    for (int j = 0; j < 24; j += 4) {
        float4 o = make_float4(fmaxf(acc2[j+0],0.f), fmaxf(acc2[j+1],0.f),
                               fmaxf(acc2[j+2],0.f), fmaxf(acc2[j+3],0.f));
        *(float4*)&Xs[lane * XSTR + c0 + j] = o;
    }
    __syncthreads();

    if (Y) {
        int r = tid >> 2, q = tid & 3;
        int v = R0 + r;
        if (v < N) {
            float4* Y4 = (float4*)Y;
#pragma unroll
            for (int k = 0; k < 6; ++k)
                Y4[v * D4 + k * 4 + q] = *(const float4*)&Xs[r * XSTR + (k * 4 + q) * 4];
        }
    }
    if (Yb) {
#pragma unroll
        for (int k = 0; k < 3; ++k) {
            int c = tid + 256 * k;          // 0..767 = 64 rows x 12 chunks
            int row = c / 12, cic = c - row * 12;
            int v = R0 + row;
            if (v < N) {
                const float* p = &Xs[row * XSTR + cic * 8];
                float4 f0 = *(const float4*)p;
                float4 f1 = *(const float4*)(p + 4);
                Yb[(size_t)v * 12 + cic] =
                    make_uint4(pack2(f0.x,f0.y), pack2(f0.z,f0.w),
                               pack2(f1.x,f1.y), pack2(f1.z,f1.w));
            }
        }
    }
}

// ======================= fallback fused fp32 layer (R6-proven) =======================
__global__ __launch_bounds__(256) void gin_layer_f32(
    const float* __restrict__ X, const int* __restrict__ rowptr,
    const int* __restrict__ esrc, const float* __restrict__ eps_p,
    const float* __restrict__ Wa, const float* __restrict__ ba,
    const float* __restrict__ Wb, const float* __restrict__ bb,
    float* __restrict__ Y, int N) {
    __shared__ float Xs[64 * XSTR];
    int tid = threadIdx.x;
    int R0 = blockIdx.x * 64;
    {
        int r = tid >> 2, q = tid & 3;
        int v = R0 + r;
        float a[24];
        if (v < N) {
            const float4* X4 = (const float4*)X;
            float s = 1.0f + eps_p[0];
#pragma unroll
            for (int i = 0; i < 6; ++i) {
                float4 xv = X4[v * D4 + 6 * q + i];
                a[4*i+0]=s*xv.x; a[4*i+1]=s*xv.y; a[4*i+2]=s*xv.z; a[4*i+3]=s*xv.w;
            }
            int e = rowptr[v], e1 = rowptr[v + 1];
            for (; e < e1; ++e) {
                int u = esrc[e] * D4 + 6 * q;
#pragma unroll
                for (int i = 0; i < 6; ++i) {
                    float4 m = X4[u + i];
                    a[4*i+0]+=m.x; a[4*i+1]+=m.y; a[4*i+2]+=m.z; a[4*i+3]+=m.w;
                }
            }
        } else {
#pragma unroll
            for (int j = 0; j < 24; ++j) a[j] = 0.f;
        }
#pragma unroll
        for (int i = 0; i < 6; ++i)
            *(float4*)&Xs[r * XSTR + q * 24 + 4 * i] =
                make_float4(a[4*i], a[4*i+1], a[4*i+2], a[4*i+3]);
    }
    __syncthreads();
    int lane = tid & 63;
    int c0 = __builtin_amdgcn_readfirstlane(tid >> 6) * 24;
    float acc[24];
#pragma unroll
    for (int j = 0; j < 24; ++j) acc[j] = ba[c0 + j];
#pragma unroll 2
    for (int k0 = 0; k0 < D; k0 += 4) {
        float4 xv = *(const float4*)&Xs[lane * XSTR + k0];
        const float* xf = (const float*)&xv;
#pragma unroll
        for (int kk = 0; kk < 4; ++kk) {
            float xx = xf[kk];
            const float* wr = &Wa[(k0 + kk) * D + c0];
#pragma unroll
            for (int j = 0; j < 24; ++j) acc[j] = fmaf(xx, wr[j], acc[j]);
        }
    }
    __syncthreads();
#pragma unroll
    for (int j = 0; j < 24; j += 4) {
        float4 h = make_float4(fmaxf(acc[j+0],0.f), fmaxf(acc[j+1],0.f),
                               fmaxf(acc[j+2],0.f), fmaxf(acc[j+3],0.f));
        *(float4*)&Xs[lane * XSTR + c0 + j] = h;
    }
    __syncthreads();
    float acc2[24];
#pragma unroll
    for (int j = 0; j < 24; ++j) acc2[j] = bb[c0 + j];
#pragma unroll 2
    for (int k0 = 0; k0 < D; k0 += 4) {
        float4 xv = *(const float4*)&Xs[lane * XSTR + k0];
        const float* xf = (const float*)&xv;
#pragma unroll
        for (int kk = 0; kk < 4; ++kk) {
            float xx = xf[kk];
            const float* wr = &Wb[(k0 + kk) * D + c0];
#pragma unroll
            for (int j = 0; j < 24; ++j) acc2[j] = fmaf(xx, wr[j], acc2[j]);
        }
    }
    __syncthreads();
#pragma unroll
    for (int j = 0; j < 24; j += 4) {
        float4 o = make_float4(fmaxf(acc2[j+0],0.f), fmaxf(acc2[j+1],0.f),
                               fmaxf(acc2[j+2],0.f), fmaxf(acc2[j+3],0.f));
        *(float4*)&Xs[lane * XSTR + c0 + j] = o;
    }
    __syncthreads();
    {
        int r = tid >> 2, q = tid & 3;
        int v = R0 + r;
        if (v < N) {
            float4* Y4 = (float4*)Y;
#pragma unroll
            for (int k = 0; k < 6; ++k)
                Y4[v * D4 + k * 4 + q] = *(const float4*)&Xs[r * XSTR + (k * 4 + q) * 4];
        }
    }
}

// ======================= launch =======================

extern "C" void kernel_launch(void* const* d_in, const int* in_sizes, int n_in,
                              void* d_out, int out_size, void* d_ws, size_t ws_size,
                              hipStream_t stream) {
    const float* feat = (const float*)d_in[0];
    const int*   src  = (const int*)d_in[1];
    const int*   dst  = (const int*)d_in[2];
    const float* eps1 = (const float*)d_in[3];
    const float* W1a  = (const float*)d_in[4];
    const float* b1a  = (const float*)d_in[5];
    const float* W1b  = (const float*)d_in[6];
    const float* b1b  = (const float*)d_in[7];
    const float* eps2 = (const float*)d_in[8];
    const float* W2a  = (const float*)d_in[9];
    const float* b2a  = (const float*)d_in[10];
    const float* W2b  = (const float*)d_in[11];
    const float* b2b  = (const float*)d_in[12];

    int N = in_sizes[0] / D;     // 50000
    int E = in_sizes[1];         // 800000
    float* out = (float*)d_out;

    int CAP = (E / NBK) + 16384;                 // bucket capacity (>40 sigma slack)

    char* w = (char*)d_ws;
    size_t off = 0;
    auto carve = [&](size_t bytes) -> void* {
        void* p = w + off;
        off += (bytes + 255) & ~(size_t)255;
        return p;
    };
    int*   rowptr = (int*)carve((size_t)(N + 1) * sizeof(int));
    int*   deg    = (int*)carve((size_t)N * sizeof(int));
    int*   cursor = (int*)carve((size_t)N * sizeof(int));
    int*   esrc   = (int*)carve((size_t)E * sizeof(int));
    int nb = (N + 1023) / 1024;
    int*   bsums  = (int*)carve((size_t)nb * sizeof(int));
    int*   boff   = (int*)carve((size_t)nb * sizeof(int));
    int*   ctrs   = (int*)carve(32 * sizeof(int));     // bctr[8], claimH[8], claimF[8]
    bool csr_ok = (off <= ws_size);
    size_t base = off;
    uint2* bstage = (uint2*)carve((size_t)NBK * CAP * sizeof(uint2));   // ~7.4 MB
    uint4* featb  = (uint4*)carve((size_t)N * 12 * sizeof(uint4));      // 9.6 MB
    uint4* Ab     = (uint4*)carve((size_t)N * 12 * sizeof(uint4));      // 9.6 MB
    bool full_ok = (off <= ws_size);
    float* A = (float*)(w + base);                                      // fallback alias
    bool a_ok = (base + (size_t)N * D * sizeof(float) <= ws_size);

    int eGrid = (E + 255) / 256;
    int layerGrid = (N + 63) / 64;
    int cvtGrid = (N * 12 + 255) / 256;
    int bucketGrid = (E + TILE - 1) / TILE;

    int* bctr = ctrs;
    int* claimH = ctrs + 8;
    int* claimF = ctrs + 16;

    if (csr_ok && full_ok) {
        (void)hipMemsetAsync(deg, 0, (size_t)N * sizeof(int), stream);
        (void)hipMemsetAsync(cursor, 0, (size_t)N * sizeof(int), stream);
        (void)hipMemsetAsync(ctrs, 0, 32 * sizeof(int), stream);

        // ---- bucketed CSR build ----
        bucketA<<<bucketGrid, 256, 0, stream>>>(src, dst, bstage, bctr, E, N, CAP);
        phaseB<0><<<768, 256, 0, stream>>>(bstage, bctr, claimH, deg,
                                           nullptr, nullptr, nullptr, CAP);
        block_sums<<<nb, 256, 0, stream>>>(deg, bsums, N);
        scan_small<<<1, 64, 0, stream>>>(bsums, boff, rowptr + N, nb);
        scan_write<<<nb, 256, 0, stream>>>(deg, boff, rowptr, N);
        phaseB<1><<<768, 256, 0, stream>>>(bstage, bctr, claimF, nullptr,
                                           rowptr, cursor, esrc, CAP);

        // ---- layers (fused, bf16 table in/out) ----
        to_bf16<<<cvtGrid, 256, 0, stream>>>((const float4*)feat, featb, N * 12);
        gin_layer_bf16<<<layerGrid, 256, 0, stream>>>(
            featb, rowptr, esrc, eps1, W1a, b1a, W1b, b1b, nullptr, Ab, N);
        gin_layer_bf16<<<layerGrid, 256, 0, stream>>>(
            Ab, rowptr, esrc, eps2, W2a, b2a, W2b, b2b, out, nullptr, N);
    } else if (csr_ok && a_ok) {
        // ---- fallback: R6-proven fp32 path with simple CSR ----
        (void)hipMemsetAsync(deg, 0, (size_t)N * sizeof(int), stream);
        hist_kernel<<<eGrid, 256, 0, stream>>>(dst, deg, E);
        block_sums<<<nb, 256, 0, stream>>>(deg, bsums, N);
        scan_small<<<1, 64, 0, stream>>>(bsums, boff, rowptr + N, nb);
        scan_write<<<nb, 256, 0, stream>>>(deg, boff, rowptr, N);
        (void)hipMemcpyAsync(cursor, rowptr, (size_t)N * sizeof(int),
                             hipMemcpyDeviceToDevice, stream);
        fill_edges<<<eGrid, 256, 0, stream>>>(src, dst, cursor, esrc, E);
        gin_layer_f32<<<layerGrid, 256, 0, stream>>>(feat, rowptr, esrc, eps1,
                                                     W1a, b1a, W1b, b1b, A, N);
        gin_layer_f32<<<layerGrid, 256, 0, stream>>>(A, rowptr, esrc, eps2,
                                                     W2a, b2a, W2b, b2b, out, N);
    }
}

// Round 12
// 184.876 us; speedup vs baseline: 2.2516x; 1.8868x over previous
//
#include <hip/hip_runtime.h>

#define D 96
#define D4 24
#define XSTR 100
#define ELLW 64        // ELL width (Poisson-16 degree; >20 sigma headroom)
typedef unsigned int uint;
typedef unsigned short ushort;

// ---------- bf16 helpers (RNE) ----------
__device__ __forceinline__ ushort f2bf(float f) {
    uint u = __float_as_uint(f);
    u = (u + 0x7FFFu + ((u >> 16) & 1u)) >> 16;
    return (ushort)u;
}
__device__ __forceinline__ uint pack2(float a, float b) {
    return (uint)f2bf(a) | ((uint)f2bf(b) << 16);
}
__device__ __forceinline__ void add8(float* a, uint4 c) {
    a[0] += __uint_as_float(c.x << 16);
    a[1] += __uint_as_float(c.x & 0xFFFF0000u);
    a[2] += __uint_as_float(c.y << 16);
    a[3] += __uint_as_float(c.y & 0xFFFF0000u);
    a[4] += __uint_as_float(c.z << 16);
    a[5] += __uint_as_float(c.z & 0xFFFF0000u);
    a[6] += __uint_as_float(c.w << 16);
    a[7] += __uint_as_float(c.w & 0xFFFF0000u);
}
__device__ __forceinline__ void set8s(float* a, uint4 c, float s) {
    a[0] = s * __uint_as_float(c.x << 16);
    a[1] = s * __uint_as_float(c.x & 0xFFFF0000u);
    a[2] = s * __uint_as_float(c.y << 16);
    a[3] = s * __uint_as_float(c.y & 0xFFFF0000u);
    a[4] = s * __uint_as_float(c.z << 16);
    a[5] = s * __uint_as_float(c.z & 0xFFFF0000u);
    a[6] = s * __uint_as_float(c.w << 16);
    a[7] = s * __uint_as_float(c.w & 0xFFFF0000u);
}

// fp32 [N][96] -> bf16 chunks [N*12] uint4
__global__ void to_bf16(const float4* __restrict__ X4, uint4* __restrict__ Xb4, int nchunk) {
    int i = blockIdx.x * blockDim.x + threadIdx.x;
    if (i >= nchunk) return;
    float4 a = X4[2 * i], b = X4[2 * i + 1];
    uint4 o;
    o.x = pack2(a.x, a.y); o.y = pack2(a.z, a.w);
    o.z = pack2(b.x, b.y); o.w = pack2(b.z, b.w);
    Xb4[i] = o;
}

// ======================= ELL build (single pass, no scan) =======================
__global__ void fill_ell(const int* __restrict__ src, const int* __restrict__ dst,
                         int* __restrict__ cnt, int* __restrict__ ell, int E) {
    int e = blockIdx.x * blockDim.x + threadIdx.x;
    if (e >= E) return;
    int d = dst[e];
    int pos = atomicAdd(&cnt[d], 1);
    if (pos < ELLW) ell[(size_t)d * ELLW + pos] = src[e];
}

// ======================= fused GIN layer (ELL, bf16 table) =======================
// Block = 64 nodes, 256 threads. Gather: 4 threads/node (r=tid>>2, q=tid&3), thread q
// owns cols [24q,24q+24) = chunks 3q..3q+2 (48B/lane; lanes 0-3 cover the 192B row).
// MLP: wave-uniform W -> scalar loads; lane = row. Outputs optional fp32 Y / bf16 Yb.
__global__ __launch_bounds__(256) void gin_layer_bf16(
    const uint4* __restrict__ Xb, const int* __restrict__ cnt,
    const int* __restrict__ ell, const float* __restrict__ eps_p,
    const float* __restrict__ Wa, const float* __restrict__ ba,
    const float* __restrict__ Wb, const float* __restrict__ bb,
    float* __restrict__ Y, uint4* __restrict__ Yb, int N) {
    __shared__ float Xs[64 * XSTR];
    int tid = threadIdx.x;
    int R0 = blockIdx.x * 64;

    // ---------- gather ----------
    {
        int r = tid >> 2, q = tid & 3;
        int v = R0 + r;
        float a[24];
        if (v < N) {
            int cb = 3 * q;
            float s = 1.0f + eps_p[0];
            const uint4* rp = Xb + (size_t)v * 12 + cb;
            uint4 c0 = rp[0], c1 = rp[1], c2 = rp[2];
            set8s(a, c0, s); set8s(a + 8, c1, s); set8s(a + 16, c2, s);
            int deg = cnt[v];
            if (deg > ELLW) deg = ELLW;
            const int* ep = ell + (size_t)v * ELLW;
            int e = 0;
            for (; e + 1 < deg; e += 2) {
                const uint4* r0 = Xb + (size_t)ep[e] * 12 + cb;
                const uint4* r1 = Xb + (size_t)ep[e + 1] * 12 + cb;
                uint4 c00 = r0[0], c01 = r0[1], c02 = r0[2];
                uint4 c10 = r1[0], c11 = r1[1], c12 = r1[2];
                add8(a + 0, c00); add8(a + 8, c01); add8(a + 16, c02);
                add8(a + 0, c10); add8(a + 8, c11); add8(a + 16, c12);
            }
            if (e < deg) {
                const uint4* r0 = Xb + (size_t)ep[e] * 12 + cb;
                add8(a + 0, r0[0]); add8(a + 8, r0[1]); add8(a + 16, r0[2]);
            }
        } else {
#pragma unroll
            for (int j = 0; j < 24; ++j) a[j] = 0.f;
        }
#pragma unroll
        for (int i = 0; i < 6; ++i)
            *(float4*)&Xs[r * XSTR + q * 24 + 4 * i] =
                make_float4(a[4*i], a[4*i+1], a[4*i+2], a[4*i+3]);
    }
    __syncthreads();

    // ---------- MLP ----------
    int lane = tid & 63;
    int c0 = __builtin_amdgcn_readfirstlane(tid >> 6) * 24;

    float acc[24];
#pragma unroll
    for (int j = 0; j < 24; ++j) acc[j] = ba[c0 + j];
#pragma unroll 2
    for (int k0 = 0; k0 < D; k0 += 4) {
        float4 xv = *(const float4*)&Xs[lane * XSTR + k0];
        const float* xf = (const float*)&xv;
#pragma unroll
        for (int kk = 0; kk < 4; ++kk) {
            float x = xf[kk];
            const float* wr = &Wa[(k0 + kk) * D + c0];
#pragma unroll
            for (int j = 0; j < 24; ++j) acc[j] = fmaf(x, wr[j], acc[j]);
        }
    }
    __syncthreads();
#pragma unroll
    for (int j = 0; j < 24; j += 4) {
        float4 h = make_float4(fmaxf(acc[j+0],0.f), fmaxf(acc[j+1],0.f),
                               fmaxf(acc[j+2],0.f), fmaxf(acc[j+3],0.f));
        *(float4*)&Xs[lane * XSTR + c0 + j] = h;
    }
    __syncthreads();

    float acc2[24];
#pragma unroll
    for (int j = 0; j < 24; ++j) acc2[j] = bb[c0 + j];
#pragma unroll 2
    for (int k0 = 0; k0 < D; k0 += 4) {
        float4 xv = *(const float4*)&Xs[lane * XSTR + k0];
        const float* xf = (const float*)&xv;
#pragma unroll
        for (int kk = 0; kk < 4; ++kk) {
            float x = xf[kk];
            const float* wr = &Wb[(k0 + kk) * D + c0];
#pragma unroll
            for (int j = 0; j < 24; ++j) acc2[j] = fmaf(x, wr[j], acc2[j]);
        }
    }
    __syncthreads();
#pragma unroll
    for (int j = 0; j < 24; j += 4) {
        float4 o = make_float4(fmaxf(acc2[j+0],0.f), fmaxf(acc2[j+1],0.f),
                               fmaxf(acc2[j+2],0.f), fmaxf(acc2[j+3],0.f));
        *(float4*)&Xs[lane * XSTR + c0 + j] = o;
    }
    __syncthreads();

    if (Y) {
        int r = tid >> 2, q = tid & 3;
        int v = R0 + r;
        if (v < N) {
            float4* Y4 = (float4*)Y;
#pragma unroll
            for (int k = 0; k < 6; ++k)
                Y4[v * D4 + k * 4 + q] = *(const float4*)&Xs[r * XSTR + (k * 4 + q) * 4];
        }
    }
    if (Yb) {
#pragma unroll
        for (int k = 0; k < 3; ++k) {
            int c = tid + 256 * k;          // 0..767 = 64 rows x 12 chunks
            int row = c / 12, cic = c - row * 12;
            int v = R0 + row;
            if (v < N) {
                const float* p = &Xs[row * XSTR + cic * 8];
                float4 f0 = *(const float4*)p;
                float4 f1 = *(const float4*)(p + 4);
                Yb[(size_t)v * 12 + cic] =
                    make_uint4(pack2(f0.x,f0.y), pack2(f0.z,f0.w),
                               pack2(f1.x,f1.y), pack2(f1.z,f1.w));
            }
        }
    }
}

// ======================= fallback: fused fp32 layer + ELL (low-ws tier) =============
__global__ __launch_bounds__(256) void gin_layer_f32(
    const float* __restrict__ X, const int* __restrict__ cnt,
    const int* __restrict__ ell, const float* __restrict__ eps_p,
    const float* __restrict__ Wa, const float* __restrict__ ba,
    const float* __restrict__ Wb, const float* __restrict__ bb,
    float* __restrict__ Y, int N) {
    __shared__ float Xs[64 * XSTR];
    int tid = threadIdx.x;
    int R0 = blockIdx.x * 64;
    {
        int r = tid >> 2, q = tid & 3;
        int v = R0 + r;
        float a[24];
        if (v < N) {
            const float4* X4 = (const float4*)X;
            float s = 1.0f + eps_p[0];
#pragma unroll
            for (int i = 0; i < 6; ++i) {
                float4 xv = X4[v * D4 + 6 * q + i];
                a[4*i+0]=s*xv.x; a[4*i+1]=s*xv.y; a[4*i+2]=s*xv.z; a[4*i+3]=s*xv.w;
            }
            int deg = cnt[v];
            if (deg > ELLW) deg = ELLW;
            const int* ep = ell + (size_t)v * ELLW;
            for (int e = 0; e < deg; ++e) {
                int u = ep[e] * D4 + 6 * q;
#pragma unroll
                for (int i = 0; i < 6; ++i) {
                    float4 m = X4[u + i];
                    a[4*i+0]+=m.x; a[4*i+1]+=m.y; a[4*i+2]+=m.z; a[4*i+3]+=m.w;
                }
            }
        } else {
#pragma unroll
            for (int j = 0; j < 24; ++j) a[j] = 0.f;
        }
#pragma unroll
        for (int i = 0; i < 6; ++i)
            *(float4*)&Xs[r * XSTR + q * 24 + 4 * i] =
                make_float4(a[4*i], a[4*i+1], a[4*i+2], a[4*i+3]);
    }
    __syncthreads();
    int lane = tid & 63;
    int c0 = __builtin_amdgcn_readfirstlane(tid >> 6) * 24;
    float acc[24];
#pragma unroll
    for (int j = 0; j < 24; ++j) acc[j] = ba[c0 + j];
#pragma unroll 2
    for (int k0 = 0; k0 < D; k0 += 4) {
        float4 xv = *(const float4*)&Xs[lane * XSTR + k0];
        const float* xf = (const float*)&xv;
#pragma unroll
        for (int kk = 0; kk < 4; ++kk) {
            float xx = xf[kk];
            const float* wr = &Wa[(k0 + kk) * D + c0];
#pragma unroll
            for (int j = 0; j < 24; ++j) acc[j] = fmaf(xx, wr[j], acc[j]);
        }
    }
    __syncthreads();
#pragma unroll
    for (int j = 0; j < 24; j += 4) {
        float4 h = make_float4(fmaxf(acc[j+0],0.f), fmaxf(acc[j+1],0.f),
                               fmaxf(acc[j+2],0.f), fmaxf(acc[j+3],0.f));
        *(float4*)&Xs[lane * XSTR + c0 + j] = h;
    }
    __syncthreads();
    float acc2[24];
#pragma unroll
    for (int j = 0; j < 24; ++j) acc2[j] = bb[c0 + j];
#pragma unroll 2
    for (int k0 = 0; k0 < D; k0 += 4) {
        float4 xv = *(const float4*)&Xs[lane * XSTR + k0];
        const float* xf = (const float*)&xv;
#pragma unroll
        for (int kk = 0; kk < 4; ++kk) {
            float xx = xf[kk];
            const float* wr = &Wb[(k0 + kk) * D + c0];
#pragma unroll
            for (int j = 0; j < 24; ++j) acc2[j] = fmaf(xx, wr[j], acc2[j]);
        }
    }
    __syncthreads();
#pragma unroll
    for (int j = 0; j < 24; j += 4) {
        float4 o = make_float4(fmaxf(acc2[j+0],0.f), fmaxf(acc2[j+1],0.f),
                               fmaxf(acc2[j+2],0.f), fmaxf(acc2[j+3],0.f));
        *(float4*)&Xs[lane * XSTR + c0 + j] = o;
    }
    __syncthreads();
    {
        int r = tid >> 2, q = tid & 3;
        int v = R0 + r;
        if (v < N) {
            float4* Y4 = (float4*)Y;
#pragma unroll
            for (int k = 0; k < 6; ++k)
                Y4[v * D4 + k * 4 + q] = *(const float4*)&Xs[r * XSTR + (k * 4 + q) * 4];
        }
    }
}

// ======================= launch =======================

extern "C" void kernel_launch(void* const* d_in, const int* in_sizes, int n_in,
                              void* d_out, int out_size, void* d_ws, size_t ws_size,
                              hipStream_t stream) {
    const float* feat = (const float*)d_in[0];
    const int*   src  = (const int*)d_in[1];
    const int*   dst  = (const int*)d_in[2];
    const float* eps1 = (const float*)d_in[3];
    const float* W1a  = (const float*)d_in[4];
    const float* b1a  = (const float*)d_in[5];
    const float* W1b  = (const float*)d_in[6];
    const float* b1b  = (const float*)d_in[7];
    const float* eps2 = (const float*)d_in[8];
    const float* W2a  = (const float*)d_in[9];
    const float* b2a  = (const float*)d_in[10];
    const float* W2b  = (const float*)d_in[11];
    const float* b2b  = (const float*)d_in[12];

    int N = in_sizes[0] / D;     // 50000
    int E = in_sizes[1];         // 800000
    float* out = (float*)d_out;

    char* w = (char*)d_ws;
    size_t off = 0;
    auto carve = [&](size_t bytes) -> void* {
        void* p = w + off;
        off += (bytes + 255) & ~(size_t)255;
        return p;
    };
    int*  cnt = (int*)carve((size_t)N * sizeof(int));                 // 200 KB
    int*  ell = (int*)carve((size_t)N * ELLW * sizeof(int));          // 12.8 MB
    bool ell_ok = (off <= ws_size);
    size_t base = off;
    uint4* featb = (uint4*)carve((size_t)N * 12 * sizeof(uint4));     // 9.6 MB
    uint4* Ab    = (uint4*)carve((size_t)N * 12 * sizeof(uint4));     // 9.6 MB
    bool full_ok = (off <= ws_size);
    float* A = (float*)(w + base);                                    // fallback alias
    bool a_ok = (base + (size_t)N * D * sizeof(float) <= ws_size);

    int eGrid = (E + 255) / 256;
    int layerGrid = (N + 63) / 64;
    int cvtGrid = (N * 12 + 255) / 256;

    if (ell_ok && (full_ok || a_ok)) {
        (void)hipMemsetAsync(cnt, 0, (size_t)N * sizeof(int), stream);
        fill_ell<<<eGrid, 256, 0, stream>>>(src, dst, cnt, ell, E);

        if (full_ok) {
            to_bf16<<<cvtGrid, 256, 0, stream>>>((const float4*)feat, featb, N * 12);
            gin_layer_bf16<<<layerGrid, 256, 0, stream>>>(
                featb, cnt, ell, eps1, W1a, b1a, W1b, b1b, nullptr, Ab, N);
            gin_layer_bf16<<<layerGrid, 256, 0, stream>>>(
                Ab, cnt, ell, eps2, W2a, b2a, W2b, b2b, out, nullptr, N);
        } else {
            gin_layer_f32<<<layerGrid, 256, 0, stream>>>(feat, cnt, ell, eps1,
                                                         W1a, b1a, W1b, b1b, A, N);
            gin_layer_f32<<<layerGrid, 256, 0, stream>>>(A, cnt, ell, eps2,
                                                         W2a, b2a, W2b, b2b, out, N);
        }
    }
}